// Round 2
// baseline (2343.367 us; speedup 1.0000x reference)
//
#include <hip/hip_runtime.h>

// Problem dims (fp32 in / fp32 out)
#define B_   64
#define T_   512
#define DIN_ 256
#define H_   512
#define DOUT_ 128

typedef _Float16 f16x8 __attribute__((ext_vector_type(8)));
typedef float f32x4  __attribute__((ext_vector_type(4)));
typedef _Float16 half2v __attribute__((ext_vector_type(2)));

// ---------------------------------------------------------------------------
// dot of 8 f16 pairs (w,h packed as uint4) accumulated into fp32
__device__ __forceinline__ float dot8(uint4 w, uint4 h, float s) {
#if __has_builtin(__builtin_amdgcn_fdot2)
  s = __builtin_amdgcn_fdot2(__builtin_bit_cast(half2v, w.x), __builtin_bit_cast(half2v, h.x), s, false);
  s = __builtin_amdgcn_fdot2(__builtin_bit_cast(half2v, w.y), __builtin_bit_cast(half2v, h.y), s, false);
  s = __builtin_amdgcn_fdot2(__builtin_bit_cast(half2v, w.z), __builtin_bit_cast(half2v, h.z), s, false);
  s = __builtin_amdgcn_fdot2(__builtin_bit_cast(half2v, w.w), __builtin_bit_cast(half2v, h.w), s, false);
#else
  const half2v* wp = (const half2v*)&w;
  const half2v* hp = (const half2v*)&h;
#pragma unroll
  for (int q = 0; q < 4; ++q) {
    s += (float)wp[q][0] * (float)hp[q][0] + (float)wp[q][1] * (float)hp[q][1];
  }
#endif
  return s;
}

// ---------------------------------------------------------------------------
// Generic fp32 -> f16 conversion (memory-bound, one-shot prep)
__global__ void cvt_f32_f16(const float* __restrict__ in, _Float16* __restrict__ out, int n) {
  int idx = blockIdx.x * 256 + threadIdx.x;
  if (idx < n) out[idx] = (_Float16)in[idx];
}

// ---------------------------------------------------------------------------
// Prep: convert W_hh (fp32, row-major HxH) into f16 streaming layout:
//   chunk c = i*512 + j  holds  W[j][i*8 .. i*8+7]   (i = k-chunk, j = row)
// so the scan's per-wave loads (lane -> consecutive chunk) are fully coalesced.
__global__ void prep_w(const float* __restrict__ w0, const float* __restrict__ w1,
                       _Float16* __restrict__ o0, _Float16* __restrict__ o1) {
  int idx = blockIdx.x * 256 + threadIdx.x;        // 0 .. 65535 (two matrices)
  const float* src = (idx < 32768) ? w0 : w1;
  _Float16* dst = (idx < 32768) ? o0 : o1;
  int c = idx & 32767;
  int i = c >> 9;        // k-chunk 0..63
  int j = c & 511;       // row
#pragma unroll
  for (int e = 0; e < 8; ++e)
    dst[(size_t)c * 8 + e] = (_Float16)src[j * 512 + i * 8 + e];
}

// ---------------------------------------------------------------------------
// GEMM: out[m,n] = sum_k X[m,k]*W[n,k] + bias1[n] + bias2[n], written as f16.
// X: M x K row-major f16 (M = 32768), W: 512 x K row-major f16 (NT-gemm).
// 128x128 tile / 256 threads / 4 waves (2x2 of 64x64), BK=32, m97-style
// global_load_lds(16B) staging, 16x16x32 f16 MFMA.
__global__ __launch_bounds__(256)
void gemm_xproj(const _Float16* __restrict__ X,
                const _Float16* __restrict__ W,
                const float* __restrict__ bias1,
                const float* __restrict__ bias2,
                _Float16* __restrict__ out, int K) {
  __shared__ __align__(16) _Float16 As[128 * 32];
  __shared__ __align__(16) _Float16 Bs[128 * 32];
  const int tid  = threadIdx.x;
  const int wave = tid >> 6;
  const int lane = tid & 63;
  const int wr = wave >> 1, wc = wave & 1;
  const int m0 = blockIdx.x * 128, n0 = blockIdx.y * 128;
  const int fr = lane & 15;
  const int fk = (lane >> 4) * 8;
  const int cA = (lane & 3) * 8;       // k-chunk within row for staging (x8 f16 = 16B)
  const int rsub = lane >> 2;          // row-within-portion for staging

  f32x4 acc[4][4];
#pragma unroll
  for (int a = 0; a < 4; ++a)
#pragma unroll
    for (int b = 0; b < 4; ++b)
      acc[a][b] = (f32x4){0.f, 0.f, 0.f, 0.f};

  for (int k0 = 0; k0 < K; k0 += 32) {
    __syncthreads();  // previous compute done before LDS overwrite
#pragma unroll
    for (int q = 0; q < 2; ++q) {
      int p = wave * 2 + q;            // portion 0..7 (16 rows = 1KB each)
      int r = p * 16 + rsub;
      const _Float16* gA = X + (size_t)(m0 + r) * K + (k0 + cA);
      const _Float16* gB = W + (size_t)(n0 + r) * K + (k0 + cA);
      __builtin_amdgcn_global_load_lds(
          (const __attribute__((address_space(1))) void*)gA,
          (__attribute__((address_space(3))) void*)((char*)As + p * 1024), 16, 0, 0);
      __builtin_amdgcn_global_load_lds(
          (const __attribute__((address_space(1))) void*)gB,
          (__attribute__((address_space(3))) void*)((char*)Bs + p * 1024), 16, 0, 0);
    }
    __syncthreads();  // compiler drains vmcnt before barrier -> LDS ready

    f16x8 af[4], bfr[4];
#pragma unroll
    for (int mt = 0; mt < 4; ++mt)
      af[mt] = *(const f16x8*)&As[(wr * 64 + mt * 16 + fr) * 32 + fk];
#pragma unroll
    for (int nt = 0; nt < 4; ++nt)
      bfr[nt] = *(const f16x8*)&Bs[(wc * 64 + nt * 16 + fr) * 32 + fk];
#pragma unroll
    for (int mt = 0; mt < 4; ++mt)
#pragma unroll
      for (int nt = 0; nt < 4; ++nt)
        acc[mt][nt] = __builtin_amdgcn_mfma_f32_16x16x32_f16(af[mt], bfr[nt], acc[mt][nt], 0, 0, 0);
  }

  // epilogue: C/D layout col = lane&15, row = (lane>>4)*4 + reg  (m89-verified)
  const int col = lane & 15, rq = lane >> 4;
#pragma unroll
  for (int nt = 0; nt < 4; ++nt) {
    int n = n0 + wc * 64 + nt * 16 + col;
    float bias = bias1[n] + bias2[n];
#pragma unroll
    for (int mt = 0; mt < 4; ++mt) {
      int mbase = m0 + wr * 64 + mt * 16 + rq * 4;
#pragma unroll
      for (int r = 0; r < 4; ++r)
        out[(size_t)(mbase + r) * H_ + n] = (_Float16)(acc[mt][nt][r] + bias);
    }
  }
}

// ---------------------------------------------------------------------------
// Recurrent scan: one workgroup per batch element, 512 threads (thread = row j).
// h_t = tanh(xproj[b,t,:] + W_hh * h_{t-1}); no inter-WG communication.
// W (f16 streaming layout) split: k-chunks 0..6 LDS-resident (56KB),
// 7..54 register-resident (192 VGPR), 55..63 streamed from L1/L2 each step.
__global__ __launch_bounds__(512)
void rnn_scan(const uint4* __restrict__ Wsu4, const _Float16* __restrict__ xproj,
              _Float16* __restrict__ seq, float* __restrict__ hlast, int mode) {
  __shared__ __align__(16) uint4 ldsW[7 * 512];     // 56 KB
  __shared__ __align__(16) _Float16 hb[2 * 512];    // double-buffered hidden state (f16)
  const int b = blockIdx.x;
  const int j = threadIdx.x;

#pragma unroll
  for (int i = 0; i < 7; ++i) ldsW[i * 512 + j] = Wsu4[i * 512 + j];
  uint4 wreg[48];
#pragma unroll
  for (int i = 0; i < 48; ++i) wreg[i] = Wsu4[(size_t)(7 + i) * 512 + j];
  hb[j] = (_Float16)0.f;
  hb[512 + j] = (_Float16)0.f;
  __syncthreads();

  const _Float16* xp = xproj + (size_t)b * (T_ * H_);
  int cur = 0;
  for (int t = 0; t < T_; ++t) {
    const uint4* hbu = (const uint4*)(hb + cur * 512);  // 64 chunks of 8 f16 (broadcast reads)
    float s = 0.f;
#pragma unroll
    for (int i = 0; i < 7; ++i)  s = dot8(ldsW[i * 512 + j], hbu[i], s);
#pragma unroll
    for (int i = 0; i < 48; ++i) s = dot8(wreg[i], hbu[7 + i], s);
#pragma unroll 3
    for (int i = 55; i < 64; ++i) s = dot8(Wsu4[(size_t)i * 512 + j], hbu[i], s);

    float hn = tanhf(s + (float)xp[t * H_ + j]);
    hb[(cur ^ 1) * 512 + j] = (_Float16)hn;
    if (mode == 0) {
      seq[(size_t)b * (T_ * H_) + t * H_ + j] = (_Float16)hn;
    } else if (t == T_ - 1) {
      hlast[b * H_ + j] = hn;
    }
    __syncthreads();
    cur ^= 1;
  }
}

// ---------------------------------------------------------------------------
// Final FC: out[b,o] = h2[b,:] . w_fc[o,:] + b_fc[o]   (64 x 128, tiny, pure fp32)
__global__ void fc_kernel(const float* __restrict__ h2,
                          const float* __restrict__ wfc,
                          const float* __restrict__ bfc,
                          float* __restrict__ out) {
  int b = blockIdx.x, o = threadIdx.x;
  float s = bfc[o];
  const float* hv = h2 + b * H_;
  const float* wr = wfc + (size_t)o * H_;
#pragma unroll 8
  for (int k = 0; k < H_; ++k) s += hv[k] * wr[k];
  out[b * DOUT_ + o] = s;
}

// ---------------------------------------------------------------------------
extern "C" void kernel_launch(void* const* d_in, const int* in_sizes, int n_in,
                              void* d_out, int out_size, void* d_ws, size_t ws_size,
                              hipStream_t stream) {
  const float* x     = (const float*)d_in[0];
  const float* w_ih0 = (const float*)d_in[1];
  const float* w_hh0 = (const float*)d_in[2];
  const float* b_ih0 = (const float*)d_in[3];
  const float* b_hh0 = (const float*)d_in[4];
  const float* w_ih1 = (const float*)d_in[5];
  const float* w_hh1 = (const float*)d_in[6];
  const float* b_ih1 = (const float*)d_in[7];
  const float* b_hh1 = (const float*)d_in[8];
  const float* w_fc  = (const float*)d_in[9];
  const float* b_fc  = (const float*)d_in[10];

  char* ws = (char*)d_ws;
  _Float16* Ws0   = (_Float16*)(ws + 0);          // 512 KB  (w_hh0 f16 streaming)
  _Float16* Ws1   = (_Float16*)(ws + 524288);     // 512 KB  (w_hh1 f16 streaming)
  _Float16* Wih0  = (_Float16*)(ws + 1048576);    // 256 KB  (w_ih0 f16)
  _Float16* Wih1  = (_Float16*)(ws + 1310720);    // 512 KB  (w_ih1 f16)
  float*    h2    = (float*)   (ws + 2097152);    // 128 KB  (final hidden, fp32)
  _Float16* xproj = (_Float16*)(ws + 4194304);    // 32 MB   REGION_A (32768x512 f16)
  _Float16* xf16  = (_Float16*)(ws + 37748736);   // REGION_B: x as f16 (16.8 MB)...
  _Float16* h1seq = (_Float16*)(ws + 37748736);   // ...then h1 sequence f16 (32 MB)
  // total ws use: ~68 MB

  // 1) one-shot conversions to f16
  cvt_f32_f16<<<32768, 256, 0, stream>>>(x, xf16, B_ * T_ * DIN_);
  cvt_f32_f16<<<512,   256, 0, stream>>>(w_ih0, Wih0, H_ * DIN_);
  cvt_f32_f16<<<1024,  256, 0, stream>>>(w_ih1, Wih1, H_ * H_);
  prep_w<<<256, 256, 0, stream>>>(w_hh0, w_hh1, Ws0, Ws1);

  // 2) xproj0 = x @ w_ih0^T + b_ih0 + b_hh0   (M=32768, K=256)
  gemm_xproj<<<dim3(256, 4), 256, 0, stream>>>(xf16, Wih0, b_ih0, b_hh0, xproj, DIN_);
  // 3) layer-0 scan -> h1seq (f16 full sequence; overwrites dead xf16 region)
  rnn_scan<<<B_, 512, 0, stream>>>((const uint4*)Ws0, xproj, h1seq, h2, 0);
  // 4) xproj1 = h1seq @ w_ih1^T + b_ih1 + b_hh1   (M=32768, K=512)
  gemm_xproj<<<dim3(256, 4), 256, 0, stream>>>(h1seq, Wih1, b_ih1, b_hh1, xproj, H_);
  // 5) layer-1 scan -> h2 (fp32 final hidden only)
  rnn_scan<<<B_, 512, 0, stream>>>((const uint4*)Ws1, xproj, h1seq, h2, 1);
  // 6) FC -> d_out (fp32, 64x128)
  fc_kernel<<<B_, DOUT_, 0, stream>>>(h2, w_fc, b_fc, (float*)d_out);
}